// Round 9
// baseline (466.191 us; speedup 1.0000x reference)
//
#include <hip/hip_runtime.h>
#include <hip/hip_fp16.h>

// GCN 2-layer: N=200000, E=6400000, 14 -> 16(relu) -> 2.
// Round 9: binA was structure-bound (44.5KB LDS -> 20% occ; 16-barrier scan +
// full LDS staging pass; 1.96M bank-conflict cyc) while FETCH/WRITE were tiny.
// The staging only existed to coalesce global writes -- but within a tile each
// bucket's ranks are consecutive, so DIRECT scatter stores land in dense ~65B
// runs (k_sort's 6.4M scattered csr stores already prove this path is cheap).
//   - binA v2: rank-capture -> pos = gofs[b]+rank -> direct global store.
//     No scan, no stage: LDS 3.1KB, 2 barriers/tile.
//   - sort v2: 1024-bin scan via wave shfl_up (3 barriers instead of ~22).
// Pipeline: binA -> sort(key=(dlow<<1)|phase; ranks from pass-1 atomics)
//   -> dinv/prep(fp16 xp) -> agg1 (2 exact phases, L2-resident gather)
//   -> mlp -> agg2.

constexpr int NN = 200000;
constexpr int NE = 6400000;
constexpr int IC = 14;
constexpr int HC = 16;
constexpr int OC = 2;

constexpr int NBK = 392;                   // buckets of 512 dst nodes
constexpr int CAP = 18432;                 // mean 16328 + ~16 sigma; = 36*512
constexpr int SCH = CAP / 512;             // 36 sort chunks
constexpr int TILE = 6400;
constexpr int IPT = TILE / 256;            // 25
constexpr int NTILE = NE / TILE;           // 1000
constexpr int OVFCAP = 65536;
constexpr int NB = (NN + 255) / 256;       // 782
constexpr int NAGG = NN / 64;              // 3125 blocks per phase
constexpr unsigned PHB = 100000u;          // phase boundary on src

typedef unsigned long long ull;

__global__ void k_flag(const void* __restrict__ ei, int* __restrict__ flag) {
    if (blockIdx.x == 0 && threadIdx.x == 0) {
        const ull* p = (const ull*)ei;
        ull acc = 0ULL;
        for (int i = 0; i < 64; ++i) acc |= (p[i] >> 32);
        *flag = (acc == 0ULL) ? 1 : 0;  // 1 => int64 indices, 0 => int32
    }
}

__global__ void k_init(int* __restrict__ gcur) {
    int t = blockIdx.x * blockDim.x + threadIdx.x;
    if (t < NBK) gcur[t] = t * CAP;
    if (t == NBK) gcur[t] = 0;  // overflow counter
}

__device__ __forceinline__ int edge_src(const void* __restrict__ ei, int fl, int e) {
    if (fl) return (int)((const long long*)ei)[e];
    return ((const int*)ei)[e];
}
__device__ __forceinline__ int edge_dst(const void* __restrict__ ei, int fl, int e) {
    if (fl) return (int)((const long long*)ei)[NE + e];
    return ((const int*)ei)[NE + e];
}

// Bin edges by dst>>9. Rank captured from the histogram atomic; edges stored
// DIRECTLY at gofs[bucket]+rank (dense ~65B runs per bucket per tile).
__global__ __launch_bounds__(256) void k_binA(const void* __restrict__ ei,
                                              const int* __restrict__ flag,
                                              int* __restrict__ gcur,
                                              unsigned* __restrict__ binned,
                                              ull* __restrict__ ovf) {
    __shared__ int hist[NBK];
    __shared__ int gofs[NBK];
    int t = threadIdx.x;
    int fl = *flag;
    int tile0 = blockIdx.x * TILE;

    if (t < NBK) hist[t] = 0;
    if (t + 256 < NBK) hist[t + 256] = 0;
    __syncthreads();

    // pass 1: dst + rank capture (dr = rank<<18 | dst)
    unsigned dr[IPT];
#pragma unroll
    for (int k = 0; k < IPT; ++k) {
        int e = tile0 + k * 256 + t;
        int d = edge_dst(ei, fl, e);
        int r = atomicAdd(&hist[d >> 9], 1);
        dr[k] = ((unsigned)r << 18) | (unsigned)d;
    }
    __syncthreads();

    if (t < NBK) gofs[t] = atomicAdd(&gcur[t], hist[t]);
    if (t + 256 < NBK) gofs[t + 256] = atomicAdd(&gcur[t + 256], hist[t + 256]);
    __syncthreads();

    // pass 2: direct scatter store
#pragma unroll
    for (int k = 0; k < IPT; ++k) {
        int e = tile0 + k * 256 + t;
        int s = edge_src(ei, fl, e);
        int d = (int)(dr[k] & 0x3FFFFu);
        int r = (int)(dr[k] >> 18);
        int b = d >> 9;
        int pos = gofs[b] + r;
        if (pos < (b + 1) * CAP) {
            binned[pos] = ((unsigned)(d & 511) << 18) | (unsigned)s;
        } else {  // overflow (never in practice)
            int op = atomicAdd(&gcur[NBK], 1);
            if (op < OVFCAP) ovf[op] = ((ull)d << 32) | (unsigned)s;
        }
    }
}

// bucket-local counting sort, key = (dlow<<1) | (src>=PHB).
// Pass 1 captures ranks from the histogram atomic; pass 2 scatters with NO
// atomics. 1024-bin exclusive scan via wave shfl_up (3 barriers).
__global__ __launch_bounds__(512) void k_sort(const int* __restrict__ gcur,
                                              const unsigned* __restrict__ binned,
                                              unsigned* __restrict__ csr,
                                              int* __restrict__ gcnt,
                                              int* __restrict__ rsg,
                                              unsigned* __restrict__ spl) {
    __shared__ int cnt[1024];
    __shared__ int excl[1024];
    __shared__ int wsum[8];
    int b = blockIdx.x;
    int t = threadIdx.x;
    cnt[t] = 0;
    cnt[t + 512] = 0;
    __syncthreads();
    int base = b * CAP;
    int n = min(gcur[b], (b + 1) * CAP) - base;

    unsigned short rank[SCH];
#pragma unroll
    for (int c = 0; c < SCH; ++c) {
        int i = c * 512 + t;
        if (i < n) {
            unsigned pack = binned[base + i];
            int key = ((int)(pack >> 18) << 1) | ((pack & 0x3FFFF) >= PHB ? 1 : 0);
            rank[c] = (unsigned short)atomicAdd(&cnt[key], 1);
        }
    }
    __syncthreads();

    // exclusive scan of 1024 counts: pair-sum + 64-lane shfl scan + wave combine
    int c0 = cnt[2 * t];
    int c1 = cnt[2 * t + 1];
    int p = c0 + c1;
    int lane = t & 63;
    int w = t >> 6;
    int incl = p;
#pragma unroll
    for (int off = 1; off < 64; off <<= 1) {
        int v = __shfl_up(incl, off, 64);
        if (lane >= off) incl += v;
    }
    if (lane == 63) wsum[w] = incl;
    __syncthreads();
    int wbase = 0;
#pragma unroll
    for (int ww = 0; ww < 8; ++ww) wbase += (ww < w) ? wsum[ww] : 0;
    int ex = wbase + incl - p;  // exclusive over bin pairs
    excl[2 * t] = ex;
    excl[2 * t + 1] = ex + c0;

    int g = (b << 9) + t;
    if (g < NN) {
        gcnt[g] = p;                                     // degree (ovf1 may add)
        rsg[g] = base + ex;                              // csr row start
        spl[g] = (unsigned)c0 | ((unsigned)c1 << 16);    // phase sub-counts
    }
    __syncthreads();

#pragma unroll
    for (int c = 0; c < SCH; ++c) {
        int i = c * 512 + t;
        if (i < n) {
            unsigned pack = binned[base + i];
            unsigned src = pack & 0x3FFFF;
            int key = ((int)(pack >> 18) << 1) | (src >= PHB ? 1 : 0);
            csr[base + excl[key] + rank[c]] = src;
        }
    }
}

__global__ void k_ovf1(const int* __restrict__ gcur, const ull* __restrict__ ovf,
                       int* __restrict__ gcnt) {
    int nov = min(gcur[NBK], OVFCAP);
    for (int i = blockIdx.x * blockDim.x + threadIdx.x; i < nov; i += gridDim.x * blockDim.x) {
        int d = (int)(ovf[i] >> 32);
        atomicAdd(&gcnt[d], 1);
    }
}

__global__ void k_dinv(const int* __restrict__ gcnt, float* __restrict__ dinv) {
    int i = blockIdx.x * blockDim.x + threadIdx.x;
    if (i < NN) dinv[i] = rsqrtf((float)gcnt[i] + 1.0f);
}

// xph[s] = fp16(dinv[s]*x[s]) padded to 16 halves (32B row); also zero aggovf.
__global__ void k_prep(const float* __restrict__ x, const float* __restrict__ dinv,
                       __half* __restrict__ xph, float* __restrict__ aggovf) {
    int i = blockIdx.x * blockDim.x + threadIdx.x;
    if (i < NN * 16) {
        int node = i >> 4;
        int c = i & 15;
        float v = (c < IC) ? dinv[node] * x[node * IC + c] : 0.0f;
        xph[i] = __float2half(v);
    } else if (i < 2 * NN * 16) {
        aggovf[i - NN * 16] = 0.0f;
    }
}

__global__ void k_ovf2(const int* __restrict__ gcur, const ull* __restrict__ ovf,
                       const __half* __restrict__ xph, float* __restrict__ aggovf) {
    int nov = min(gcur[NBK], OVFCAP);
    for (int i = blockIdx.x * blockDim.x + threadIdx.x; i < nov; i += gridDim.x * blockDim.x) {
        int d = (int)(ovf[i] >> 32);
        int s = (int)(ovf[i] & 0xFFFFFFFFu);
        for (int c = 0; c < 16; ++c)
            atomicAdd(&aggovf[(size_t)d * 16 + c], __half2float(xph[(size_t)s * 16 + c]));
    }
}

// Layer-1 aggregation. Phase q reads ONLY its csr sub-range (exact partition).
// Gather region = 3.2MB fp16, L2-resident. 4 lanes per dst node.
__global__ __launch_bounds__(256) void k_agg1(const int* __restrict__ rsg,
                                              const unsigned* __restrict__ spl,
                                              const unsigned* __restrict__ csr,
                                              const __half* __restrict__ xph,
                                              float* __restrict__ partial) {
    int t = threadIdx.x;
    int q = (blockIdx.x >= NAGG) ? 1 : 0;
    int blk = blockIdx.x - q * NAGG;
    int g = t >> 2;
    int qq = t & 3;
    int i = blk * 64 + g;
    unsigned sp = spl[i];
    int n0 = (int)(sp & 0xFFFF);
    int n1 = (int)(sp >> 16);
    int beg = rsg[i] + (q ? n0 : 0);
    int end = beg + (q ? n1 : n0);

    float ax = 0.0f, ay = 0.0f, az = 0.0f, aw = 0.0f;
    int j = beg;
    for (; j + 1 < end; j += 2) {
        int s0 = csr[j];
        int s1 = csr[j + 1];
        uint2 u0 = *(const uint2*)(xph + (size_t)s0 * 16 + 4 * qq);
        uint2 u1 = *(const uint2*)(xph + (size_t)s1 * 16 + 4 * qq);
        float2 f0 = __half22float2(*(__half2*)&u0.x);
        float2 f1 = __half22float2(*(__half2*)&u0.y);
        float2 f2 = __half22float2(*(__half2*)&u1.x);
        float2 f3 = __half22float2(*(__half2*)&u1.y);
        ax += f0.x + f2.x;
        ay += f0.y + f2.y;
        az += f1.x + f3.x;
        aw += f1.y + f3.y;
    }
    if (j < end) {
        uint2 u0 = *(const uint2*)(xph + (size_t)csr[j] * 16 + 4 * qq);
        float2 f0 = __half22float2(*(__half2*)&u0.x);
        float2 f1 = __half22float2(*(__half2*)&u0.y);
        ax += f0.x;
        ay += f0.y;
        az += f1.x;
        aw += f1.y;
    }
    float4 r = {ax, ay, az, aw};
    *(float4*)(partial + ((size_t)q * NN + i) * 16 + 4 * qq) = r;
}

// Sum phase partials + self loop + ovf, then the fused node MLP.
__global__ __launch_bounds__(256) void k_mlp(const float* __restrict__ partial,
                                             const __half* __restrict__ xph,
                                             const float* __restrict__ aggovf,
                                             const float* __restrict__ dinv,
                                             const float* __restrict__ W1,
                                             const float* __restrict__ b1,
                                             const float* __restrict__ W2,
                                             const float* __restrict__ b2,
                                             float2* __restrict__ h2bp,
                                             float2* __restrict__ selfout) {
    __shared__ float sW1[IC * HC];
    __shared__ float sb1[HC];
    __shared__ float sW2[HC * OC];
    __shared__ float sb2[OC];
    int t = threadIdx.x;
    if (t < IC * HC) sW1[t] = W1[t];
    if (t < HC) sb1[t] = b1[t];
    if (t < HC * OC) sW2[t] = W2[t];
    if (t < OC) sb2[t] = b2[t];
    __syncthreads();

    int i = blockIdx.x * 256 + t;
    if (i >= NN) return;

    float dv = dinv[i];
    const float4* p0 = (const float4*)(partial + (size_t)i * 16);
    const float4* p1 = (const float4*)(partial + ((size_t)NN + i) * 16);
    const float4* ov = (const float4*)(aggovf + (size_t)i * 16);
    const uint2* sp = (const uint2*)(xph + (size_t)i * 16);

    float agg[16];
#pragma unroll
    for (int c4 = 0; c4 < 4; ++c4) {
        float4 a = p0[c4];
        float4 b = p1[c4];
        float4 o = ov[c4];
        uint2 u = sp[c4];
        float2 s0 = __half22float2(*(__half2*)&u.x);
        float2 s1 = __half22float2(*(__half2*)&u.y);
        agg[4 * c4 + 0] = a.x + b.x + o.x + s0.x;
        agg[4 * c4 + 1] = a.y + b.y + o.y + s0.y;
        agg[4 * c4 + 2] = a.z + b.z + o.z + s1.x;
        agg[4 * c4 + 3] = a.w + b.w + o.w + s1.y;
    }

    float tt[IC];
#pragma unroll
    for (int c = 0; c < IC; ++c) tt[c] = dv * agg[c];

    float r[HC];
#pragma unroll
    for (int f = 0; f < HC; ++f) {
        float a = sb1[f];
#pragma unroll
        for (int c = 0; c < IC; ++c) a = fmaf(tt[c], sW1[c * HC + f], a);
        r[f] = fmaxf(a, 0.0f);
    }

    float o0 = 0.0f, o1 = 0.0f;
#pragma unroll
    for (int f = 0; f < HC; ++f) {
        o0 = fmaf(r[f], sW2[f * OC + 0], o0);
        o1 = fmaf(r[f], sW2[f * OC + 1], o1);
    }
    h2bp[i] = make_float2(o0 * dv, o1 * dv);  // dinv-prescaled for layer 2
    selfout[i] = make_float2(o0 * dv * dv + sb2[0], o1 * dv * dv + sb2[1]);
}

// layer-2: out[i] = selfout[i] + dinv[i] * sum h2bp[src]; h2bp (1.6MB) L2-resident
__global__ __launch_bounds__(256) void k_agg2(const int* __restrict__ rsg,
                                              const unsigned* __restrict__ spl,
                                              const unsigned* __restrict__ csr,
                                              const float* __restrict__ dinv,
                                              const float2* __restrict__ h2bp,
                                              const float2* __restrict__ selfout,
                                              float2* __restrict__ out) {
    int i = blockIdx.x * 256 + threadIdx.x;
    if (i >= NN) return;
    unsigned sp = spl[i];
    int beg = rsg[i];
    int end = beg + (int)(sp & 0xFFFF) + (int)(sp >> 16);
    float ax = 0.0f, ay = 0.0f;
    int j = beg;
    for (; j + 3 < end; j += 4) {
        float2 h0 = h2bp[csr[j]];
        float2 h1 = h2bp[csr[j + 1]];
        float2 h2 = h2bp[csr[j + 2]];
        float2 h3 = h2bp[csr[j + 3]];
        ax += (h0.x + h1.x) + (h2.x + h3.x);
        ay += (h0.y + h1.y) + (h2.y + h3.y);
    }
    for (; j < end; ++j) {
        float2 h = h2bp[csr[j]];
        ax += h.x;
        ay += h.y;
    }
    float dv = dinv[i];
    float2 so = selfout[i];
    out[i] = make_float2(so.x + dv * ax, so.y + dv * ay);
}

__global__ void k_ovf3(const int* __restrict__ gcur, const ull* __restrict__ ovf,
                       const float* __restrict__ dinv, const float2* __restrict__ h2bp,
                       float* __restrict__ out) {
    int nov = min(gcur[NBK], OVFCAP);
    for (int i = blockIdx.x * blockDim.x + threadIdx.x; i < nov; i += gridDim.x * blockDim.x) {
        int d = (int)(ovf[i] >> 32);
        int s = (int)(ovf[i] & 0xFFFFFFFFu);
        float2 h = h2bp[s];
        atomicAdd(&out[(size_t)d * OC + 0], dinv[d] * h.x);
        atomicAdd(&out[(size_t)d * OC + 1], dinv[d] * h.y);
    }
}

extern "C" void kernel_launch(void* const* d_in, const int* in_sizes, int n_in,
                              void* d_out, int out_size, void* d_ws, size_t ws_size,
                              hipStream_t stream) {
    const float* x = (const float*)d_in[0];
    const void* ei = d_in[1];
    // d_in[2] = edge_attr (unused)
    const float* W1 = (const float*)d_in[3];
    const float* b1 = (const float*)d_in[4];
    const float* W2 = (const float*)d_in[5];
    const float* b2 = (const float*)d_in[6];
    float* out = (float*)d_out;

    ull* ovf = (ull*)d_ws;                              // OVFCAP       (0.5MB)
    int* gcur = (int*)(ovf + OVFCAP);                   // 512
    int* flag = gcur + 512;                             // 4
    int* gcnt = flag + 4;                               // NN
    int* rsg = gcnt + NN;                               // NN
    unsigned* spl = (unsigned*)(rsg + NN);              // NN
    float* dinv = (float*)(spl + NN);                   // NN
    __half* xph = (__half*)(dinv + NN);                 // NN*16 halves (6.4MB)
    float* aggovf = (float*)(xph + (size_t)NN * 16);    // NN*16        (12.8MB)
    float2* h2bp = (float2*)(aggovf + (size_t)NN * 16); // NN
    float2* selfout = h2bp + NN;                        // NN
    unsigned* binned = (unsigned*)(selfout + NN);       // NBK*CAP      (28.9MB)
    float* partial = (float*)binned;                    // 2*NN*16 f32 (25.6MB), overlays
                                                        // binned (dead after k_sort)
    unsigned* csr = binned + (size_t)NBK * CAP;         // NBK*CAP      (28.9MB)

    k_flag<<<1, 64, 0, stream>>>(ei, flag);
    k_init<<<2, 256, 0, stream>>>(gcur);
    k_binA<<<NTILE, 256, 0, stream>>>(ei, flag, gcur, binned, ovf);
    k_sort<<<NBK, 512, 0, stream>>>(gcur, binned, csr, gcnt, rsg, spl);
    k_ovf1<<<8, 256, 0, stream>>>(gcur, ovf, gcnt);
    k_dinv<<<NB, 256, 0, stream>>>(gcnt, dinv);
    k_prep<<<(2 * NN * 16 + 255) / 256, 256, 0, stream>>>(x, dinv, xph, aggovf);
    k_ovf2<<<8, 256, 0, stream>>>(gcur, ovf, xph, aggovf);
    k_agg1<<<2 * NAGG, 256, 0, stream>>>(rsg, spl, csr, xph, partial);
    k_mlp<<<NB, 256, 0, stream>>>(partial, xph, aggovf, dinv, W1, b1, W2, b2, h2bp, selfout);
    k_agg2<<<NB, 256, 0, stream>>>(rsg, spl, csr, dinv, h2bp, selfout, (float2*)out);
    k_ovf3<<<8, 256, 0, stream>>>(gcur, ovf, dinv, h2bp, out);
}

// Round 10
// 419.087 us; speedup vs baseline: 1.1124x; 1.1124x over previous
//
#include <hip/hip_runtime.h>
#include <hip/hip_fp16.h>

// GCN 2-layer: N=200000, E=6400000, 14 -> 16(relu) -> 2.
// Round 10: revert R9's direct-scatter binA (WRITE 36->134MB, 5x amplification,
// 140us -- pre-registered failure criterion hit). Staged write-out restored,
// with two fixes to R8's structural costs:
//   - scan via 64-lane shfl_up + wave combine (2 barriers, was 16)
//   - TILE 6400->5120: stage LDS 44.5->34.6KB -> 4 blocks/CU (was 3), grid 1250
// Keep: sort v2 (shfl scan, rank-capture, zero pass-2 atomics), exact-phase
// agg1 (fp16 xp, L2-resident 3.2MB region), fused mlp, agg2.

constexpr int NN = 200000;
constexpr int NE = 6400000;
constexpr int IC = 14;
constexpr int HC = 16;
constexpr int OC = 2;

constexpr int NBK = 392;                   // buckets of 512 dst nodes
constexpr int CAP = 18432;                 // mean 16328 + ~16 sigma; = 36*512
constexpr int SCH = CAP / 512;             // 36 sort chunks
constexpr int TILE = 5120;                 // edges per binA tile
constexpr int IPT = TILE / 256;            // 20
constexpr int NTILE = NE / TILE;           // 1250
constexpr int OVFCAP = 65536;
constexpr int NB = (NN + 255) / 256;       // 782
constexpr int NAGG = NN / 64;              // 3125 blocks per phase
constexpr unsigned PHB = 100000u;          // phase boundary on src

typedef unsigned long long ull;

__global__ void k_flag(const void* __restrict__ ei, int* __restrict__ flag) {
    if (blockIdx.x == 0 && threadIdx.x == 0) {
        const ull* p = (const ull*)ei;
        ull acc = 0ULL;
        for (int i = 0; i < 64; ++i) acc |= (p[i] >> 32);
        *flag = (acc == 0ULL) ? 1 : 0;  // 1 => int64 indices, 0 => int32
    }
}

__global__ void k_init(int* __restrict__ gcur) {
    int t = blockIdx.x * blockDim.x + threadIdx.x;
    if (t < NBK) gcur[t] = t * CAP;
    if (t == NBK) gcur[t] = 0;  // overflow counter
}

__device__ __forceinline__ int edge_src(const void* __restrict__ ei, int fl, int e) {
    if (fl) return (int)((const long long*)ei)[e];
    return ((const int*)ei)[e];
}
__device__ __forceinline__ int edge_dst(const void* __restrict__ ei, int fl, int e) {
    if (fl) return (int)((const long long*)ei)[NE + e];
    return ((const int*)ei)[NE + e];
}

// Bin edges by dst>>9 into 392 global segments. Rank captured from the
// histogram atomic; LDS-staged for coalesced segment write-out.
__global__ __launch_bounds__(256) void k_binA(const void* __restrict__ ei,
                                              const int* __restrict__ flag,
                                              int* __restrict__ gcur,
                                              unsigned* __restrict__ binned,
                                              ull* __restrict__ ovf) {
    __shared__ int hist[NBK];
    __shared__ int lofs[NBK];
    __shared__ int gofs[NBK];
    __shared__ int wsum[4];
    __shared__ unsigned stage[TILE];
    __shared__ unsigned short sb[TILE];

    int t = threadIdx.x;
    int fl = *flag;
    int tile0 = blockIdx.x * TILE;

    if (t < NBK) hist[t] = 0;
    if (t + 256 < NBK) hist[t + 256] = 0;
    __syncthreads();

    // pass 1: dst + rank capture (dr = rank<<18 | dst)
    unsigned dr[IPT];
#pragma unroll
    for (int k = 0; k < IPT; ++k) {
        int e = tile0 + k * 256 + t;
        int d = edge_dst(ei, fl, e);
        int r = atomicAdd(&hist[d >> 9], 1);
        dr[k] = ((unsigned)r << 18) | (unsigned)d;
    }
    __syncthreads();

    // exclusive scan of 392 counts: pair-sum + 64-lane shfl scan + wave combine
    int h0 = 0, h1 = 0, p = 0;
    if (t < NBK / 2) {
        h0 = hist[2 * t];
        h1 = hist[2 * t + 1];
        p = h0 + h1;
    }
    int lane = t & 63;
    int w = t >> 6;
    int incl = p;
#pragma unroll
    for (int off = 1; off < 64; off <<= 1) {
        int v = __shfl_up(incl, off, 64);
        if (lane >= off) incl += v;
    }
    if (lane == 63) wsum[w] = incl;
    __syncthreads();
    int wbase = 0;
#pragma unroll
    for (int ww = 0; ww < 4; ++ww) wbase += (ww < w) ? wsum[ww] : 0;
    int ex = wbase + incl - p;
    if (t < NBK / 2) {
        lofs[2 * t] = ex;
        lofs[2 * t + 1] = ex + h0;
    }
    if (t < NBK) gofs[t] = atomicAdd(&gcur[t], hist[t]);
    if (t + 256 < NBK) gofs[t + 256] = atomicAdd(&gcur[t + 256], hist[t + 256]);
    __syncthreads();

    // stage at lofs[bucket] + rank (no second atomic)
#pragma unroll
    for (int k = 0; k < IPT; ++k) {
        int e = tile0 + k * 256 + t;
        int s = edge_src(ei, fl, e);
        int d = (int)(dr[k] & 0x3FFFFu);
        int r = (int)(dr[k] >> 18);
        int b = d >> 9;
        int pos = lofs[b] + r;
        stage[pos] = ((unsigned)(d & 511) << 18) | (unsigned)s;
        sb[pos] = (unsigned short)b;
    }
    __syncthreads();

    // coalesced write-out: consecutive i within a bucket -> consecutive dest
    for (int i = t; i < TILE; i += 256) {
        int b = sb[i];
        unsigned pack = stage[i];
        int dest = gofs[b] + (i - lofs[b]);
        if (dest < (b + 1) * CAP) {
            binned[dest] = pack;
        } else {  // overflow (never in practice)
            int op = atomicAdd(&gcur[NBK], 1);
            if (op < OVFCAP) {
                int d = (b << 9) | (int)(pack >> 18);
                int s = (int)(pack & 0x3FFFF);
                ovf[op] = ((ull)d << 32) | (unsigned)s;
            }
        }
    }
}

// bucket-local counting sort, key = (dlow<<1) | (src>=PHB).
// Pass 1 captures ranks from the histogram atomic; pass 2 scatters with NO
// atomics. 1024-bin exclusive scan via wave shfl_up (3 barriers).
__global__ __launch_bounds__(512) void k_sort(const int* __restrict__ gcur,
                                              const unsigned* __restrict__ binned,
                                              unsigned* __restrict__ csr,
                                              int* __restrict__ gcnt,
                                              int* __restrict__ rsg,
                                              unsigned* __restrict__ spl) {
    __shared__ int cnt[1024];
    __shared__ int excl[1024];
    __shared__ int wsum[8];
    int b = blockIdx.x;
    int t = threadIdx.x;
    cnt[t] = 0;
    cnt[t + 512] = 0;
    __syncthreads();
    int base = b * CAP;
    int n = min(gcur[b], (b + 1) * CAP) - base;

    unsigned short rank[SCH];
#pragma unroll
    for (int c = 0; c < SCH; ++c) {
        int i = c * 512 + t;
        if (i < n) {
            unsigned pack = binned[base + i];
            int key = ((int)(pack >> 18) << 1) | ((pack & 0x3FFFF) >= PHB ? 1 : 0);
            rank[c] = (unsigned short)atomicAdd(&cnt[key], 1);
        }
    }
    __syncthreads();

    // exclusive scan of 1024 counts: pair-sum + 64-lane shfl scan + wave combine
    int c0 = cnt[2 * t];
    int c1 = cnt[2 * t + 1];
    int p = c0 + c1;
    int lane = t & 63;
    int w = t >> 6;
    int incl = p;
#pragma unroll
    for (int off = 1; off < 64; off <<= 1) {
        int v = __shfl_up(incl, off, 64);
        if (lane >= off) incl += v;
    }
    if (lane == 63) wsum[w] = incl;
    __syncthreads();
    int wbase = 0;
#pragma unroll
    for (int ww = 0; ww < 8; ++ww) wbase += (ww < w) ? wsum[ww] : 0;
    int ex = wbase + incl - p;  // exclusive over bin pairs
    excl[2 * t] = ex;
    excl[2 * t + 1] = ex + c0;

    int g = (b << 9) + t;
    if (g < NN) {
        gcnt[g] = p;                                     // degree (ovf1 may add)
        rsg[g] = base + ex;                              // csr row start
        spl[g] = (unsigned)c0 | ((unsigned)c1 << 16);    // phase sub-counts
    }
    __syncthreads();

#pragma unroll
    for (int c = 0; c < SCH; ++c) {
        int i = c * 512 + t;
        if (i < n) {
            unsigned pack = binned[base + i];
            unsigned src = pack & 0x3FFFF;
            int key = ((int)(pack >> 18) << 1) | (src >= PHB ? 1 : 0);
            csr[base + excl[key] + rank[c]] = src;
        }
    }
}

__global__ void k_ovf1(const int* __restrict__ gcur, const ull* __restrict__ ovf,
                       int* __restrict__ gcnt) {
    int nov = min(gcur[NBK], OVFCAP);
    for (int i = blockIdx.x * blockDim.x + threadIdx.x; i < nov; i += gridDim.x * blockDim.x) {
        int d = (int)(ovf[i] >> 32);
        atomicAdd(&gcnt[d], 1);
    }
}

__global__ void k_dinv(const int* __restrict__ gcnt, float* __restrict__ dinv) {
    int i = blockIdx.x * blockDim.x + threadIdx.x;
    if (i < NN) dinv[i] = rsqrtf((float)gcnt[i] + 1.0f);
}

// xph[s] = fp16(dinv[s]*x[s]) padded to 16 halves (32B row); also zero aggovf.
__global__ void k_prep(const float* __restrict__ x, const float* __restrict__ dinv,
                       __half* __restrict__ xph, float* __restrict__ aggovf) {
    int i = blockIdx.x * blockDim.x + threadIdx.x;
    if (i < NN * 16) {
        int node = i >> 4;
        int c = i & 15;
        float v = (c < IC) ? dinv[node] * x[node * IC + c] : 0.0f;
        xph[i] = __float2half(v);
    } else if (i < 2 * NN * 16) {
        aggovf[i - NN * 16] = 0.0f;
    }
}

__global__ void k_ovf2(const int* __restrict__ gcur, const ull* __restrict__ ovf,
                       const __half* __restrict__ xph, float* __restrict__ aggovf) {
    int nov = min(gcur[NBK], OVFCAP);
    for (int i = blockIdx.x * blockDim.x + threadIdx.x; i < nov; i += gridDim.x * blockDim.x) {
        int d = (int)(ovf[i] >> 32);
        int s = (int)(ovf[i] & 0xFFFFFFFFu);
        for (int c = 0; c < 16; ++c)
            atomicAdd(&aggovf[(size_t)d * 16 + c], __half2float(xph[(size_t)s * 16 + c]));
    }
}

// Layer-1 aggregation. Phase q reads ONLY its csr sub-range (exact partition).
// Gather region = 3.2MB fp16, L2-resident. 4 lanes per dst node.
__global__ __launch_bounds__(256) void k_agg1(const int* __restrict__ rsg,
                                              const unsigned* __restrict__ spl,
                                              const unsigned* __restrict__ csr,
                                              const __half* __restrict__ xph,
                                              float* __restrict__ partial) {
    int t = threadIdx.x;
    int q = (blockIdx.x >= NAGG) ? 1 : 0;
    int blk = blockIdx.x - q * NAGG;
    int g = t >> 2;
    int qq = t & 3;
    int i = blk * 64 + g;
    unsigned sp = spl[i];
    int n0 = (int)(sp & 0xFFFF);
    int n1 = (int)(sp >> 16);
    int beg = rsg[i] + (q ? n0 : 0);
    int end = beg + (q ? n1 : n0);

    float ax = 0.0f, ay = 0.0f, az = 0.0f, aw = 0.0f;
    int j = beg;
    for (; j + 1 < end; j += 2) {
        int s0 = csr[j];
        int s1 = csr[j + 1];
        uint2 u0 = *(const uint2*)(xph + (size_t)s0 * 16 + 4 * qq);
        uint2 u1 = *(const uint2*)(xph + (size_t)s1 * 16 + 4 * qq);
        float2 f0 = __half22float2(*(__half2*)&u0.x);
        float2 f1 = __half22float2(*(__half2*)&u0.y);
        float2 f2 = __half22float2(*(__half2*)&u1.x);
        float2 f3 = __half22float2(*(__half2*)&u1.y);
        ax += f0.x + f2.x;
        ay += f0.y + f2.y;
        az += f1.x + f3.x;
        aw += f1.y + f3.y;
    }
    if (j < end) {
        uint2 u0 = *(const uint2*)(xph + (size_t)csr[j] * 16 + 4 * qq);
        float2 f0 = __half22float2(*(__half2*)&u0.x);
        float2 f1 = __half22float2(*(__half2*)&u0.y);
        ax += f0.x;
        ay += f0.y;
        az += f1.x;
        aw += f1.y;
    }
    float4 r = {ax, ay, az, aw};
    *(float4*)(partial + ((size_t)q * NN + i) * 16 + 4 * qq) = r;
}

// Sum phase partials + self loop + ovf, then the fused node MLP.
__global__ __launch_bounds__(256) void k_mlp(const float* __restrict__ partial,
                                             const __half* __restrict__ xph,
                                             const float* __restrict__ aggovf,
                                             const float* __restrict__ dinv,
                                             const float* __restrict__ W1,
                                             const float* __restrict__ b1,
                                             const float* __restrict__ W2,
                                             const float* __restrict__ b2,
                                             float2* __restrict__ h2bp,
                                             float2* __restrict__ selfout) {
    __shared__ float sW1[IC * HC];
    __shared__ float sb1[HC];
    __shared__ float sW2[HC * OC];
    __shared__ float sb2[OC];
    int t = threadIdx.x;
    if (t < IC * HC) sW1[t] = W1[t];
    if (t < HC) sb1[t] = b1[t];
    if (t < HC * OC) sW2[t] = W2[t];
    if (t < OC) sb2[t] = b2[t];
    __syncthreads();

    int i = blockIdx.x * 256 + t;
    if (i >= NN) return;

    float dv = dinv[i];
    const float4* p0 = (const float4*)(partial + (size_t)i * 16);
    const float4* p1 = (const float4*)(partial + ((size_t)NN + i) * 16);
    const float4* ov = (const float4*)(aggovf + (size_t)i * 16);
    const uint2* sp = (const uint2*)(xph + (size_t)i * 16);

    float agg[16];
#pragma unroll
    for (int c4 = 0; c4 < 4; ++c4) {
        float4 a = p0[c4];
        float4 b = p1[c4];
        float4 o = ov[c4];
        uint2 u = sp[c4];
        float2 s0 = __half22float2(*(__half2*)&u.x);
        float2 s1 = __half22float2(*(__half2*)&u.y);
        agg[4 * c4 + 0] = a.x + b.x + o.x + s0.x;
        agg[4 * c4 + 1] = a.y + b.y + o.y + s0.y;
        agg[4 * c4 + 2] = a.z + b.z + o.z + s1.x;
        agg[4 * c4 + 3] = a.w + b.w + o.w + s1.y;
    }

    float tt[IC];
#pragma unroll
    for (int c = 0; c < IC; ++c) tt[c] = dv * agg[c];

    float r[HC];
#pragma unroll
    for (int f = 0; f < HC; ++f) {
        float a = sb1[f];
#pragma unroll
        for (int c = 0; c < IC; ++c) a = fmaf(tt[c], sW1[c * HC + f], a);
        r[f] = fmaxf(a, 0.0f);
    }

    float o0 = 0.0f, o1 = 0.0f;
#pragma unroll
    for (int f = 0; f < HC; ++f) {
        o0 = fmaf(r[f], sW2[f * OC + 0], o0);
        o1 = fmaf(r[f], sW2[f * OC + 1], o1);
    }
    h2bp[i] = make_float2(o0 * dv, o1 * dv);  // dinv-prescaled for layer 2
    selfout[i] = make_float2(o0 * dv * dv + sb2[0], o1 * dv * dv + sb2[1]);
}

// layer-2: out[i] = selfout[i] + dinv[i] * sum h2bp[src]; h2bp (1.6MB) L2-resident
__global__ __launch_bounds__(256) void k_agg2(const int* __restrict__ rsg,
                                              const unsigned* __restrict__ spl,
                                              const unsigned* __restrict__ csr,
                                              const float* __restrict__ dinv,
                                              const float2* __restrict__ h2bp,
                                              const float2* __restrict__ selfout,
                                              float2* __restrict__ out) {
    int i = blockIdx.x * 256 + threadIdx.x;
    if (i >= NN) return;
    unsigned sp = spl[i];
    int beg = rsg[i];
    int end = beg + (int)(sp & 0xFFFF) + (int)(sp >> 16);
    float ax = 0.0f, ay = 0.0f;
    int j = beg;
    for (; j + 3 < end; j += 4) {
        float2 h0 = h2bp[csr[j]];
        float2 h1 = h2bp[csr[j + 1]];
        float2 h2 = h2bp[csr[j + 2]];
        float2 h3 = h2bp[csr[j + 3]];
        ax += (h0.x + h1.x) + (h2.x + h3.x);
        ay += (h0.y + h1.y) + (h2.y + h3.y);
    }
    for (; j < end; ++j) {
        float2 h = h2bp[csr[j]];
        ax += h.x;
        ay += h.y;
    }
    float dv = dinv[i];
    float2 so = selfout[i];
    out[i] = make_float2(so.x + dv * ax, so.y + dv * ay);
}

__global__ void k_ovf3(const int* __restrict__ gcur, const ull* __restrict__ ovf,
                       const float* __restrict__ dinv, const float2* __restrict__ h2bp,
                       float* __restrict__ out) {
    int nov = min(gcur[NBK], OVFCAP);
    for (int i = blockIdx.x * blockDim.x + threadIdx.x; i < nov; i += gridDim.x * blockDim.x) {
        int d = (int)(ovf[i] >> 32);
        int s = (int)(ovf[i] & 0xFFFFFFFFu);
        float2 h = h2bp[s];
        atomicAdd(&out[(size_t)d * OC + 0], dinv[d] * h.x);
        atomicAdd(&out[(size_t)d * OC + 1], dinv[d] * h.y);
    }
}

extern "C" void kernel_launch(void* const* d_in, const int* in_sizes, int n_in,
                              void* d_out, int out_size, void* d_ws, size_t ws_size,
                              hipStream_t stream) {
    const float* x = (const float*)d_in[0];
    const void* ei = d_in[1];
    // d_in[2] = edge_attr (unused)
    const float* W1 = (const float*)d_in[3];
    const float* b1 = (const float*)d_in[4];
    const float* W2 = (const float*)d_in[5];
    const float* b2 = (const float*)d_in[6];
    float* out = (float*)d_out;

    ull* ovf = (ull*)d_ws;                              // OVFCAP       (0.5MB)
    int* gcur = (int*)(ovf + OVFCAP);                   // 512
    int* flag = gcur + 512;                             // 4
    int* gcnt = flag + 4;                               // NN
    int* rsg = gcnt + NN;                               // NN
    unsigned* spl = (unsigned*)(rsg + NN);              // NN
    float* dinv = (float*)(spl + NN);                   // NN
    __half* xph = (__half*)(dinv + NN);                 // NN*16 halves (6.4MB)
    float* aggovf = (float*)(xph + (size_t)NN * 16);    // NN*16        (12.8MB)
    float2* h2bp = (float2*)(aggovf + (size_t)NN * 16); // NN
    float2* selfout = h2bp + NN;                        // NN
    unsigned* binned = (unsigned*)(selfout + NN);       // NBK*CAP      (28.9MB)
    float* partial = (float*)binned;                    // 2*NN*16 f32 (25.6MB), overlays
                                                        // binned (dead after k_sort)
    unsigned* csr = binned + (size_t)NBK * CAP;         // NBK*CAP      (28.9MB)

    k_flag<<<1, 64, 0, stream>>>(ei, flag);
    k_init<<<2, 256, 0, stream>>>(gcur);
    k_binA<<<NTILE, 256, 0, stream>>>(ei, flag, gcur, binned, ovf);
    k_sort<<<NBK, 512, 0, stream>>>(gcur, binned, csr, gcnt, rsg, spl);
    k_ovf1<<<8, 256, 0, stream>>>(gcur, ovf, gcnt);
    k_dinv<<<NB, 256, 0, stream>>>(gcnt, dinv);
    k_prep<<<(2 * NN * 16 + 255) / 256, 256, 0, stream>>>(x, dinv, xph, aggovf);
    k_ovf2<<<8, 256, 0, stream>>>(gcur, ovf, xph, aggovf);
    k_agg1<<<2 * NAGG, 256, 0, stream>>>(rsg, spl, csr, xph, partial);
    k_mlp<<<NB, 256, 0, stream>>>(partial, xph, aggovf, dinv, W1, b1, W2, b2, h2bp, selfout);
    k_agg2<<<NB, 256, 0, stream>>>(rsg, spl, csr, dinv, h2bp, selfout, (float2*)out);
    k_ovf3<<<8, 256, 0, stream>>>(gcur, ovf, dinv, h2bp, out);
}

// Round 11
// 399.322 us; speedup vs baseline: 1.1675x; 1.0495x over previous
//
#include <hip/hip_runtime.h>
#include <hip/hip_fp16.h>

// GCN 2-layer: N=200000, E=6400000, 14 -> 16(relu) -> 2.
// Round 11: binA was bound by 490k device-scope atomics on 392 counters packed
// into 25 cache lines (~20k serialized ops/line at one L2 slice ~= the whole
// 88us). Fixes:
//   - gcur padded to 1 counter / 64B line (stride 16): contention/line 20k->1250.
//   - pipeline 12 -> 7 kernels: flag folded into init; k_dinv deleted (sort
//     computes dinv from its own histogram + ovf scan); ovf1->sort, ovf2->mlp
//     (aggovf buffer eliminated), ovf3->agg2. All ovf paths remain (scans of a
//     normally-empty list, free when nov==0).
//   - agg2: 2 lanes/node + shfl_xor combine (dependent-load latency bound).
// Pipeline: init -> binA -> sort(+dinv) -> prep -> agg1(2 phase) -> mlp -> agg2.

constexpr int NN = 200000;
constexpr int NE = 6400000;
constexpr int IC = 14;
constexpr int HC = 16;
constexpr int OC = 2;

constexpr int NBK = 392;                   // buckets of 512 dst nodes
constexpr int CAP = 18432;                 // mean 16328 + ~16 sigma; = 36*512
constexpr int SCH = CAP / 512;             // 36 sort chunks
constexpr int TILE = 5120;                 // edges per binA tile
constexpr int IPT = TILE / 256;            // 20
constexpr int NTILE = NE / TILE;           // 1250
constexpr int OVFCAP = 65536;
constexpr int NB = (NN + 255) / 256;       // 782
constexpr int NAGG = NN / 64;              // 3125 blocks per phase
constexpr unsigned PHB = 100000u;          // phase boundary on src
constexpr int GSTR = 16;                   // gcur stride: 1 counter per 64B line

typedef unsigned long long ull;

// init gcur (padded) + ovf counter + dtype flag
__global__ void k_init(int* __restrict__ gcur, const void* __restrict__ ei,
                       int* __restrict__ flag) {
    int i = blockIdx.x * blockDim.x + threadIdx.x;
    if (i < NBK) gcur[i * GSTR] = i * CAP;
    else if (i == NBK) gcur[i * GSTR] = 0;  // overflow counter
    if (i == 500) {  // one thread sniffs edge dtype
        const ull* p = (const ull*)ei;
        ull acc = 0ULL;
        for (int k = 0; k < 64; ++k) acc |= (p[k] >> 32);
        *flag = (acc == 0ULL) ? 1 : 0;  // 1 => int64 indices, 0 => int32
    }
}

__device__ __forceinline__ int edge_src(const void* __restrict__ ei, int fl, int e) {
    if (fl) return (int)((const long long*)ei)[e];
    return ((const int*)ei)[e];
}
__device__ __forceinline__ int edge_dst(const void* __restrict__ ei, int fl, int e) {
    if (fl) return (int)((const long long*)ei)[NE + e];
    return ((const int*)ei)[NE + e];
}

// Bin edges by dst>>9 into 392 global segments. Rank captured from the
// histogram atomic; LDS-staged for coalesced segment write-out.
__global__ __launch_bounds__(256) void k_binA(const void* __restrict__ ei,
                                              const int* __restrict__ flag,
                                              int* __restrict__ gcur,
                                              unsigned* __restrict__ binned,
                                              ull* __restrict__ ovf) {
    __shared__ int hist[NBK];
    __shared__ int lofs[NBK];
    __shared__ int gofs[NBK];
    __shared__ int wsum[4];
    __shared__ unsigned stage[TILE];
    __shared__ unsigned short sb[TILE];

    int t = threadIdx.x;
    int fl = *flag;
    int tile0 = blockIdx.x * TILE;

    if (t < NBK) hist[t] = 0;
    if (t + 256 < NBK) hist[t + 256] = 0;
    __syncthreads();

    // pass 1: dst + rank capture (dr = rank<<18 | dst)
    unsigned dr[IPT];
#pragma unroll
    for (int k = 0; k < IPT; ++k) {
        int e = tile0 + k * 256 + t;
        int d = edge_dst(ei, fl, e);
        int r = atomicAdd(&hist[d >> 9], 1);
        dr[k] = ((unsigned)r << 18) | (unsigned)d;
    }
    __syncthreads();

    // exclusive scan of 392 counts: pair-sum + 64-lane shfl scan + wave combine
    int h0 = 0, h1 = 0, p = 0;
    if (t < NBK / 2) {
        h0 = hist[2 * t];
        h1 = hist[2 * t + 1];
        p = h0 + h1;
    }
    int lane = t & 63;
    int w = t >> 6;
    int incl = p;
#pragma unroll
    for (int off = 1; off < 64; off <<= 1) {
        int v = __shfl_up(incl, off, 64);
        if (lane >= off) incl += v;
    }
    if (lane == 63) wsum[w] = incl;
    __syncthreads();
    int wbase = 0;
#pragma unroll
    for (int ww = 0; ww < 4; ++ww) wbase += (ww < w) ? wsum[ww] : 0;
    int ex = wbase + incl - p;
    if (t < NBK / 2) {
        lofs[2 * t] = ex;
        lofs[2 * t + 1] = ex + h0;
    }
    if (t < NBK) gofs[t] = atomicAdd(&gcur[t * GSTR], hist[t]);
    if (t + 256 < NBK) gofs[t + 256] = atomicAdd(&gcur[(t + 256) * GSTR], hist[t + 256]);
    __syncthreads();

    // stage at lofs[bucket] + rank (no second atomic)
#pragma unroll
    for (int k = 0; k < IPT; ++k) {
        int e = tile0 + k * 256 + t;
        int s = edge_src(ei, fl, e);
        int d = (int)(dr[k] & 0x3FFFFu);
        int r = (int)(dr[k] >> 18);
        int b = d >> 9;
        int pos = lofs[b] + r;
        stage[pos] = ((unsigned)(d & 511) << 18) | (unsigned)s;
        sb[pos] = (unsigned short)b;
    }
    __syncthreads();

    // coalesced write-out: consecutive i within a bucket -> consecutive dest
    for (int i = t; i < TILE; i += 256) {
        int b = sb[i];
        unsigned pack = stage[i];
        int dest = gofs[b] + (i - lofs[b]);
        if (dest < (b + 1) * CAP) {
            binned[dest] = pack;
        } else {  // overflow (never in practice)
            int op = atomicAdd(&gcur[NBK * GSTR], 1);
            if (op < OVFCAP) {
                int d = (b << 9) | (int)(pack >> 18);
                int s = (int)(pack & 0x3FFFF);
                ovf[op] = ((ull)d << 32) | (unsigned)s;
            }
        }
    }
}

// bucket-local counting sort, key = (dlow<<1) | (src>=PHB).
// Pass 1 captures ranks from the histogram atomic; pass 2 scatters with NO
// atomics. Also computes dinv = rsqrt(degree+1) directly (degree = own
// histogram pair + overflow-list matches).
__global__ __launch_bounds__(512) void k_sort(const int* __restrict__ gcur,
                                              const unsigned* __restrict__ binned,
                                              const ull* __restrict__ ovf,
                                              unsigned* __restrict__ csr,
                                              float* __restrict__ dinv,
                                              int* __restrict__ rsg,
                                              unsigned* __restrict__ spl) {
    __shared__ int cnt[1024];
    __shared__ int excl[1024];
    __shared__ int wsum[8];
    int b = blockIdx.x;
    int t = threadIdx.x;
    cnt[t] = 0;
    cnt[t + 512] = 0;
    __syncthreads();
    int base = b * CAP;
    int n = min(gcur[b * GSTR], (b + 1) * CAP) - base;
    int nov = min(gcur[NBK * GSTR], OVFCAP);

    unsigned short rank[SCH];
#pragma unroll
    for (int c = 0; c < SCH; ++c) {
        int i = c * 512 + t;
        if (i < n) {
            unsigned pack = binned[base + i];
            int key = ((int)(pack >> 18) << 1) | ((pack & 0x3FFFF) >= PHB ? 1 : 0);
            rank[c] = (unsigned short)atomicAdd(&cnt[key], 1);
        }
    }
    __syncthreads();

    // exclusive scan of 1024 counts: pair-sum + 64-lane shfl scan + wave combine
    int c0 = cnt[2 * t];
    int c1 = cnt[2 * t + 1];
    int p = c0 + c1;
    int lane = t & 63;
    int w = t >> 6;
    int incl = p;
#pragma unroll
    for (int off = 1; off < 64; off <<= 1) {
        int v = __shfl_up(incl, off, 64);
        if (lane >= off) incl += v;
    }
    if (lane == 63) wsum[w] = incl;
    __syncthreads();
    int wbase = 0;
#pragma unroll
    for (int ww = 0; ww < 8; ++ww) wbase += (ww < w) ? wsum[ww] : 0;
    int ex = wbase + incl - p;  // exclusive over bin pairs
    excl[2 * t] = ex;
    excl[2 * t + 1] = ex + c0;

    int g = (b << 9) + t;
    if (g < NN) {
        int extra = 0;
        for (int k = 0; k < nov; ++k) extra += ((int)(ovf[k] >> 32) == g);
        dinv[g] = rsqrtf((float)(p + extra) + 1.0f);
        rsg[g] = base + ex;                              // csr row start
        spl[g] = (unsigned)c0 | ((unsigned)c1 << 16);    // phase sub-counts
    }
    __syncthreads();

#pragma unroll
    for (int c = 0; c < SCH; ++c) {
        int i = c * 512 + t;
        if (i < n) {
            unsigned pack = binned[base + i];
            unsigned src = pack & 0x3FFFF;
            int key = ((int)(pack >> 18) << 1) | (src >= PHB ? 1 : 0);
            csr[base + excl[key] + rank[c]] = src;
        }
    }
}

// xph[s] = fp16(dinv[s]*x[s]) padded to 16 halves (one aligned 32B row).
__global__ void k_prep(const float* __restrict__ x, const float* __restrict__ dinv,
                       __half* __restrict__ xph) {
    int i = blockIdx.x * blockDim.x + threadIdx.x;
    if (i >= NN * 16) return;
    int node = i >> 4;
    int c = i & 15;
    float v = (c < IC) ? dinv[node] * x[node * IC + c] : 0.0f;
    xph[i] = __float2half(v);
}

// Layer-1 aggregation. Phase q reads ONLY its csr sub-range (exact partition).
// Gather region = 3.2MB fp16, L2-resident. 4 lanes per dst node.
__global__ __launch_bounds__(256) void k_agg1(const int* __restrict__ rsg,
                                              const unsigned* __restrict__ spl,
                                              const unsigned* __restrict__ csr,
                                              const __half* __restrict__ xph,
                                              float* __restrict__ partial) {
    int t = threadIdx.x;
    int q = (blockIdx.x >= NAGG) ? 1 : 0;
    int blk = blockIdx.x - q * NAGG;
    int g = t >> 2;
    int qq = t & 3;
    int i = blk * 64 + g;
    unsigned sp = spl[i];
    int n0 = (int)(sp & 0xFFFF);
    int n1 = (int)(sp >> 16);
    int beg = rsg[i] + (q ? n0 : 0);
    int end = beg + (q ? n1 : n0);

    float ax = 0.0f, ay = 0.0f, az = 0.0f, aw = 0.0f;
    int j = beg;
    for (; j + 1 < end; j += 2) {
        int s0 = csr[j];
        int s1 = csr[j + 1];
        uint2 u0 = *(const uint2*)(xph + (size_t)s0 * 16 + 4 * qq);
        uint2 u1 = *(const uint2*)(xph + (size_t)s1 * 16 + 4 * qq);
        float2 f0 = __half22float2(*(__half2*)&u0.x);
        float2 f1 = __half22float2(*(__half2*)&u0.y);
        float2 f2 = __half22float2(*(__half2*)&u1.x);
        float2 f3 = __half22float2(*(__half2*)&u1.y);
        ax += f0.x + f2.x;
        ay += f0.y + f2.y;
        az += f1.x + f3.x;
        aw += f1.y + f3.y;
    }
    if (j < end) {
        uint2 u0 = *(const uint2*)(xph + (size_t)csr[j] * 16 + 4 * qq);
        float2 f0 = __half22float2(*(__half2*)&u0.x);
        float2 f1 = __half22float2(*(__half2*)&u0.y);
        ax += f0.x;
        ay += f0.y;
        az += f1.x;
        aw += f1.y;
    }
    float4 r = {ax, ay, az, aw};
    *(float4*)(partial + ((size_t)q * NN + i) * 16 + 4 * qq) = r;
}

// Sum phase partials + self loop + overflow-list fixup, then the fused MLP.
__global__ __launch_bounds__(256) void k_mlp(const float* __restrict__ partial,
                                             const __half* __restrict__ xph,
                                             const int* __restrict__ gcur,
                                             const ull* __restrict__ ovf,
                                             const float* __restrict__ dinv,
                                             const float* __restrict__ W1,
                                             const float* __restrict__ b1,
                                             const float* __restrict__ W2,
                                             const float* __restrict__ b2,
                                             float2* __restrict__ h2bp,
                                             float2* __restrict__ selfout) {
    __shared__ float sW1[IC * HC];
    __shared__ float sb1[HC];
    __shared__ float sW2[HC * OC];
    __shared__ float sb2[OC];
    int t = threadIdx.x;
    if (t < IC * HC) sW1[t] = W1[t];
    if (t < HC) sb1[t] = b1[t];
    if (t < HC * OC) sW2[t] = W2[t];
    if (t < OC) sb2[t] = b2[t];
    __syncthreads();

    int i = blockIdx.x * 256 + t;
    if (i >= NN) return;

    float dv = dinv[i];
    const float4* p0 = (const float4*)(partial + (size_t)i * 16);
    const float4* p1 = (const float4*)(partial + ((size_t)NN + i) * 16);
    const uint2* sp = (const uint2*)(xph + (size_t)i * 16);

    float agg[16];
#pragma unroll
    for (int c4 = 0; c4 < 4; ++c4) {
        float4 a = p0[c4];
        float4 b = p1[c4];
        uint2 u = sp[c4];
        float2 s0 = __half22float2(*(__half2*)&u.x);
        float2 s1 = __half22float2(*(__half2*)&u.y);
        agg[4 * c4 + 0] = a.x + b.x + s0.x;
        agg[4 * c4 + 1] = a.y + b.y + s0.y;
        agg[4 * c4 + 2] = a.z + b.z + s1.x;
        agg[4 * c4 + 3] = a.w + b.w + s1.y;
    }

    // overflow fixup (nov==0 in practice)
    int nov = min(gcur[NBK * GSTR], OVFCAP);
    for (int k = 0; k < nov; ++k) {
        ull e = ovf[k];
        if ((int)(e >> 32) == i) {
            int s = (int)(e & 0xFFFFFFFFu);
            for (int c = 0; c < IC; ++c)
                agg[c] += __half2float(xph[(size_t)s * 16 + c]);
        }
    }

    float tt[IC];
#pragma unroll
    for (int c = 0; c < IC; ++c) tt[c] = dv * agg[c];

    float r[HC];
#pragma unroll
    for (int f = 0; f < HC; ++f) {
        float a = sb1[f];
#pragma unroll
        for (int c = 0; c < IC; ++c) a = fmaf(tt[c], sW1[c * HC + f], a);
        r[f] = fmaxf(a, 0.0f);
    }

    float o0 = 0.0f, o1 = 0.0f;
#pragma unroll
    for (int f = 0; f < HC; ++f) {
        o0 = fmaf(r[f], sW2[f * OC + 0], o0);
        o1 = fmaf(r[f], sW2[f * OC + 1], o1);
    }
    h2bp[i] = make_float2(o0 * dv, o1 * dv);  // dinv-prescaled for layer 2
    selfout[i] = make_float2(o0 * dv * dv + sb2[0], o1 * dv * dv + sb2[1]);
}

// layer-2: out[i] = selfout[i] + dinv[i] * (sum h2bp[src] + ovf matches).
// 2 lanes per node (split edge range), shfl_xor combine.
__global__ __launch_bounds__(256) void k_agg2(const int* __restrict__ rsg,
                                              const unsigned* __restrict__ spl,
                                              const unsigned* __restrict__ csr,
                                              const int* __restrict__ gcur,
                                              const ull* __restrict__ ovf,
                                              const float* __restrict__ dinv,
                                              const float2* __restrict__ h2bp,
                                              const float2* __restrict__ selfout,
                                              float2* __restrict__ out) {
    int tt = blockIdx.x * 256 + threadIdx.x;
    int i = tt >> 1;
    int h = tt & 1;
    if (i >= NN) return;
    unsigned sp = spl[i];
    int beg = rsg[i];
    int end = beg + (int)(sp & 0xFFFF) + (int)(sp >> 16);
    float ax = 0.0f, ay = 0.0f;
    int j = beg + h;
    for (; j + 2 < end; j += 4) {
        float2 h0 = h2bp[csr[j]];
        float2 h1 = h2bp[csr[j + 2]];
        ax += h0.x + h1.x;
        ay += h0.y + h1.y;
    }
    if (j < end) {
        float2 h0 = h2bp[csr[j]];
        ax += h0.x;
        ay += h0.y;
    }
    ax += __shfl_xor(ax, 1);
    ay += __shfl_xor(ay, 1);
    if (h == 0) {
        // overflow fixup (nov==0 in practice); h2bp already dinv[src]-prescaled
        int nov = min(gcur[NBK * GSTR], OVFCAP);
        for (int k = 0; k < nov; ++k) {
            ull e = ovf[k];
            if ((int)(e >> 32) == i) {
                float2 hh = h2bp[(int)(e & 0xFFFFFFFFu)];
                ax += hh.x;
                ay += hh.y;
            }
        }
        float dv = dinv[i];
        float2 so = selfout[i];
        out[i] = make_float2(so.x + dv * ax, so.y + dv * ay);
    }
}

extern "C" void kernel_launch(void* const* d_in, const int* in_sizes, int n_in,
                              void* d_out, int out_size, void* d_ws, size_t ws_size,
                              hipStream_t stream) {
    const float* x = (const float*)d_in[0];
    const void* ei = d_in[1];
    // d_in[2] = edge_attr (unused)
    const float* W1 = (const float*)d_in[3];
    const float* b1 = (const float*)d_in[4];
    const float* W2 = (const float*)d_in[5];
    const float* b2 = (const float*)d_in[6];
    float* out = (float*)d_out;

    ull* ovf = (ull*)d_ws;                              // OVFCAP       (0.5MB)
    int* gcur = (int*)(ovf + OVFCAP);                   // (NBK+1)*16 -> pad 6400
    int* flag = gcur + 6400;                            // 4
    int* rsg = flag + 4;                                // NN
    unsigned* spl = (unsigned*)(rsg + NN);              // NN
    float* dinv = (float*)(spl + NN);                   // NN
    __half* xph = (__half*)(dinv + NN);                 // NN*16 halves (6.4MB)
    float2* h2bp = (float2*)(xph + (size_t)NN * 16);    // NN
    float2* selfout = h2bp + NN;                        // NN
    unsigned* binned = (unsigned*)(selfout + NN);       // NBK*CAP      (28.9MB)
    float* partial = (float*)binned;                    // 2*NN*16 f32 (25.6MB), overlays
                                                        // binned (dead after k_sort)
    unsigned* csr = binned + (size_t)NBK * CAP;         // NBK*CAP      (28.9MB)

    k_init<<<2, 256, 0, stream>>>(gcur, ei, flag);
    k_binA<<<NTILE, 256, 0, stream>>>(ei, flag, gcur, binned, ovf);
    k_sort<<<NBK, 512, 0, stream>>>(gcur, binned, ovf, csr, dinv, rsg, spl);
    k_prep<<<(NN * 16 + 255) / 256, 256, 0, stream>>>(x, dinv, xph);
    k_agg1<<<2 * NAGG, 256, 0, stream>>>(rsg, spl, csr, xph, partial);
    k_mlp<<<NB, 256, 0, stream>>>(partial, xph, gcur, ovf, dinv, W1, b1, W2, b2,
                                  h2bp, selfout);
    k_agg2<<<(NN * 2 + 255) / 256, 256, 0, stream>>>(rsg, spl, csr, gcur, ovf, dinv,
                                                     h2bp, selfout, (float2*)out);
}

// Round 12
// 393.577 us; speedup vs baseline: 1.1845x; 1.0146x over previous
//
#include <hip/hip_runtime.h>
#include <hip/hip_fp16.h>

// GCN 2-layer: N=200000, E=6400000, 14 -> 16(relu) -> 2.
// Round 12: binA is latency-bound at ~15% utilization with only 4 blocks/CU
// (35.8KB LDS). Occupancy push:
//   - binA: sb[] (10KB) deleted; write-out derives bucket via 9-step binary
//     search over sorted lofs[] in LDS (idle pipes -> free). 25.2KB -> 6
//     blocks/CU (24 waves, was 16).
//   - sort: 1024 threads/block -> 392 blocks all co-resident in ONE scheduling
//     round (was 1.53 rounds of 512-thread blocks); thread-per-bin scan.
// Pipeline: init -> binA -> sort(+dinv) -> prep -> agg1(2 phase) -> mlp -> agg2.

constexpr int NN = 200000;
constexpr int NE = 6400000;
constexpr int IC = 14;
constexpr int HC = 16;
constexpr int OC = 2;

constexpr int NBK = 392;                   // buckets of 512 dst nodes
constexpr int CAP = 18432;                 // mean 16328 + ~16 sigma; = 18*1024
constexpr int SCH = CAP / 1024;            // 18 sort chunks (1024 threads)
constexpr int TILE = 5120;                 // edges per binA tile
constexpr int IPT = TILE / 256;            // 20
constexpr int NTILE = NE / TILE;           // 1250
constexpr int OVFCAP = 65536;
constexpr int NB = (NN + 255) / 256;       // 782
constexpr int NAGG = NN / 64;              // 3125 blocks per phase
constexpr unsigned PHB = 100000u;          // phase boundary on src
constexpr int GSTR = 16;                   // gcur stride: 1 counter per 64B line

typedef unsigned long long ull;

// init gcur (padded) + ovf counter + dtype flag
__global__ void k_init(int* __restrict__ gcur, const void* __restrict__ ei,
                       int* __restrict__ flag) {
    int i = blockIdx.x * blockDim.x + threadIdx.x;
    if (i < NBK) gcur[i * GSTR] = i * CAP;
    else if (i == NBK) gcur[i * GSTR] = 0;  // overflow counter
    if (i == 500) {  // one thread sniffs edge dtype
        const ull* p = (const ull*)ei;
        ull acc = 0ULL;
        for (int k = 0; k < 64; ++k) acc |= (p[k] >> 32);
        *flag = (acc == 0ULL) ? 1 : 0;  // 1 => int64 indices, 0 => int32
    }
}

__device__ __forceinline__ int edge_src(const void* __restrict__ ei, int fl, int e) {
    if (fl) return (int)((const long long*)ei)[e];
    return ((const int*)ei)[e];
}
__device__ __forceinline__ int edge_dst(const void* __restrict__ ei, int fl, int e) {
    if (fl) return (int)((const long long*)ei)[NE + e];
    return ((const int*)ei)[NE + e];
}

// Bin edges by dst>>9 into 392 global segments. Rank captured from the
// histogram atomic; LDS-staged for coalesced segment write-out. Bucket of a
// stage slot recovered by binary search over lofs (sorted prefix offsets).
__global__ __launch_bounds__(256, 6) void k_binA(const void* __restrict__ ei,
                                                 const int* __restrict__ flag,
                                                 int* __restrict__ gcur,
                                                 unsigned* __restrict__ binned,
                                                 ull* __restrict__ ovf) {
    __shared__ int hist[NBK];
    __shared__ int lofs[NBK];
    __shared__ int gofs[NBK];
    __shared__ int wsum[4];
    __shared__ unsigned stage[TILE];

    int t = threadIdx.x;
    int fl = *flag;
    int tile0 = blockIdx.x * TILE;

    if (t < NBK) hist[t] = 0;
    if (t + 256 < NBK) hist[t + 256] = 0;
    __syncthreads();

    // pass 1: dst + rank capture (dr = rank<<18 | dst)
    unsigned dr[IPT];
#pragma unroll
    for (int k = 0; k < IPT; ++k) {
        int e = tile0 + k * 256 + t;
        int d = edge_dst(ei, fl, e);
        int r = atomicAdd(&hist[d >> 9], 1);
        dr[k] = ((unsigned)r << 18) | (unsigned)d;
    }
    __syncthreads();

    // exclusive scan of 392 counts: pair-sum + 64-lane shfl scan + wave combine
    int h0 = 0, h1 = 0, p = 0;
    if (t < NBK / 2) {
        h0 = hist[2 * t];
        h1 = hist[2 * t + 1];
        p = h0 + h1;
    }
    int lane = t & 63;
    int w = t >> 6;
    int incl = p;
#pragma unroll
    for (int off = 1; off < 64; off <<= 1) {
        int v = __shfl_up(incl, off, 64);
        if (lane >= off) incl += v;
    }
    if (lane == 63) wsum[w] = incl;
    __syncthreads();
    int wbase = 0;
#pragma unroll
    for (int ww = 0; ww < 4; ++ww) wbase += (ww < w) ? wsum[ww] : 0;
    int ex = wbase + incl - p;
    if (t < NBK / 2) {
        lofs[2 * t] = ex;
        lofs[2 * t + 1] = ex + h0;
    }
    if (t < NBK) gofs[t] = atomicAdd(&gcur[t * GSTR], hist[t]);
    if (t + 256 < NBK) gofs[t + 256] = atomicAdd(&gcur[(t + 256) * GSTR], hist[t + 256]);
    __syncthreads();

    // stage at lofs[bucket] + rank (no second atomic)
#pragma unroll
    for (int k = 0; k < IPT; ++k) {
        int e = tile0 + k * 256 + t;
        int s = edge_src(ei, fl, e);
        int d = (int)(dr[k] & 0x3FFFFu);
        int r = (int)(dr[k] >> 18);
        int b = d >> 9;
        int pos = lofs[b] + r;
        stage[pos] = ((unsigned)(d & 511) << 18) | (unsigned)s;
    }
    __syncthreads();

    // coalesced write-out; bucket of slot i via binary search on lofs
    for (int i = t; i < TILE; i += 256) {
        int lo = 0, hi = NBK - 1;
#pragma unroll
        for (int it = 0; it < 9; ++it) {
            int mid = (lo + hi + 1) >> 1;
            if (lofs[mid] <= i) lo = mid;
            else hi = mid - 1;
        }
        int b = lo;
        unsigned pack = stage[i];
        int dest = gofs[b] + (i - lofs[b]);
        if (dest < (b + 1) * CAP) {
            binned[dest] = pack;
        } else {  // overflow (never in practice)
            int op = atomicAdd(&gcur[NBK * GSTR], 1);
            if (op < OVFCAP) {
                int d = (b << 9) | (int)(pack >> 18);
                int s = (int)(pack & 0x3FFFF);
                ovf[op] = ((ull)d << 32) | (unsigned)s;
            }
        }
    }
}

// bucket-local counting sort, key = (dlow<<1) | (src>=PHB). 1024 threads:
// thread t owns bin t; ranks from pass-1 atomics; no pass-2 atomics.
// Also computes dinv = rsqrt(degree+1) (degree = histogram pair + ovf matches).
__global__ __launch_bounds__(1024, 8) void k_sort(const int* __restrict__ gcur,
                                                  const unsigned* __restrict__ binned,
                                                  const ull* __restrict__ ovf,
                                                  unsigned* __restrict__ csr,
                                                  float* __restrict__ dinv,
                                                  int* __restrict__ rsg,
                                                  unsigned* __restrict__ spl) {
    __shared__ int cnt[1024];
    __shared__ int excl[1024];
    __shared__ int wsum[16];
    int b = blockIdx.x;
    int t = threadIdx.x;
    cnt[t] = 0;
    __syncthreads();
    int base = b * CAP;
    int n = min(gcur[b * GSTR], (b + 1) * CAP) - base;
    int nov = min(gcur[NBK * GSTR], OVFCAP);

    unsigned short rank[SCH];
#pragma unroll
    for (int c = 0; c < SCH; ++c) {
        int i = c * 1024 + t;
        if (i < n) {
            unsigned pack = binned[base + i];
            int key = ((int)(pack >> 18) << 1) | ((pack & 0x3FFFF) >= PHB ? 1 : 0);
            rank[c] = (unsigned short)atomicAdd(&cnt[key], 1);
        }
    }
    __syncthreads();

    // exclusive scan of 1024 counts: 64-lane shfl scan + 16-wave combine
    int c = cnt[t];
    int lane = t & 63;
    int w = t >> 6;
    int incl = c;
#pragma unroll
    for (int off = 1; off < 64; off <<= 1) {
        int v = __shfl_up(incl, off, 64);
        if (lane >= off) incl += v;
    }
    if (lane == 63) wsum[w] = incl;
    __syncthreads();
    int wbase = 0;
#pragma unroll
    for (int ww = 0; ww < 16; ++ww) wbase += (ww < w) ? wsum[ww] : 0;
    excl[t] = wbase + incl - c;
    __syncthreads();

    if (t < 512) {
        int g = (b << 9) + t;
        if (g < NN) {
            int c0 = cnt[2 * t];
            int c1 = cnt[2 * t + 1];
            int extra = 0;
            for (int k = 0; k < nov; ++k) extra += ((int)(ovf[k] >> 32) == g);
            dinv[g] = rsqrtf((float)(c0 + c1 + extra) + 1.0f);
            rsg[g] = base + excl[2 * t];                     // csr row start
            spl[g] = (unsigned)c0 | ((unsigned)c1 << 16);    // phase sub-counts
        }
    }

#pragma unroll
    for (int cc = 0; cc < SCH; ++cc) {
        int i = cc * 1024 + t;
        if (i < n) {
            unsigned pack = binned[base + i];
            unsigned src = pack & 0x3FFFF;
            int key = ((int)(pack >> 18) << 1) | (src >= PHB ? 1 : 0);
            csr[base + excl[key] + rank[cc]] = src;
        }
    }
}

// xph[s] = fp16(dinv[s]*x[s]) padded to 16 halves (one aligned 32B row).
__global__ void k_prep(const float* __restrict__ x, const float* __restrict__ dinv,
                       __half* __restrict__ xph) {
    int i = blockIdx.x * blockDim.x + threadIdx.x;
    if (i >= NN * 16) return;
    int node = i >> 4;
    int c = i & 15;
    float v = (c < IC) ? dinv[node] * x[node * IC + c] : 0.0f;
    xph[i] = __float2half(v);
}

// Layer-1 aggregation. Phase q reads ONLY its csr sub-range (exact partition).
// Gather region = 3.2MB fp16, L2-resident. 4 lanes per dst node.
__global__ __launch_bounds__(256) void k_agg1(const int* __restrict__ rsg,
                                              const unsigned* __restrict__ spl,
                                              const unsigned* __restrict__ csr,
                                              const __half* __restrict__ xph,
                                              float* __restrict__ partial) {
    int t = threadIdx.x;
    int q = (blockIdx.x >= NAGG) ? 1 : 0;
    int blk = blockIdx.x - q * NAGG;
    int g = t >> 2;
    int qq = t & 3;
    int i = blk * 64 + g;
    unsigned sp = spl[i];
    int n0 = (int)(sp & 0xFFFF);
    int n1 = (int)(sp >> 16);
    int beg = rsg[i] + (q ? n0 : 0);
    int end = beg + (q ? n1 : n0);

    float ax = 0.0f, ay = 0.0f, az = 0.0f, aw = 0.0f;
    int j = beg;
    for (; j + 1 < end; j += 2) {
        int s0 = csr[j];
        int s1 = csr[j + 1];
        uint2 u0 = *(const uint2*)(xph + (size_t)s0 * 16 + 4 * qq);
        uint2 u1 = *(const uint2*)(xph + (size_t)s1 * 16 + 4 * qq);
        float2 f0 = __half22float2(*(__half2*)&u0.x);
        float2 f1 = __half22float2(*(__half2*)&u0.y);
        float2 f2 = __half22float2(*(__half2*)&u1.x);
        float2 f3 = __half22float2(*(__half2*)&u1.y);
        ax += f0.x + f2.x;
        ay += f0.y + f2.y;
        az += f1.x + f3.x;
        aw += f1.y + f3.y;
    }
    if (j < end) {
        uint2 u0 = *(const uint2*)(xph + (size_t)csr[j] * 16 + 4 * qq);
        float2 f0 = __half22float2(*(__half2*)&u0.x);
        float2 f1 = __half22float2(*(__half2*)&u0.y);
        ax += f0.x;
        ay += f0.y;
        az += f1.x;
        aw += f1.y;
    }
    float4 r = {ax, ay, az, aw};
    *(float4*)(partial + ((size_t)q * NN + i) * 16 + 4 * qq) = r;
}

// Sum phase partials + self loop + overflow-list fixup, then the fused MLP.
__global__ __launch_bounds__(256) void k_mlp(const float* __restrict__ partial,
                                             const __half* __restrict__ xph,
                                             const int* __restrict__ gcur,
                                             const ull* __restrict__ ovf,
                                             const float* __restrict__ dinv,
                                             const float* __restrict__ W1,
                                             const float* __restrict__ b1,
                                             const float* __restrict__ W2,
                                             const float* __restrict__ b2,
                                             float2* __restrict__ h2bp,
                                             float2* __restrict__ selfout) {
    __shared__ float sW1[IC * HC];
    __shared__ float sb1[HC];
    __shared__ float sW2[HC * OC];
    __shared__ float sb2[OC];
    int t = threadIdx.x;
    if (t < IC * HC) sW1[t] = W1[t];
    if (t < HC) sb1[t] = b1[t];
    if (t < HC * OC) sW2[t] = W2[t];
    if (t < OC) sb2[t] = b2[t];
    __syncthreads();

    int i = blockIdx.x * 256 + t;
    if (i >= NN) return;

    float dv = dinv[i];
    const float4* p0 = (const float4*)(partial + (size_t)i * 16);
    const float4* p1 = (const float4*)(partial + ((size_t)NN + i) * 16);
    const uint2* sp = (const uint2*)(xph + (size_t)i * 16);

    float agg[16];
#pragma unroll
    for (int c4 = 0; c4 < 4; ++c4) {
        float4 a = p0[c4];
        float4 b = p1[c4];
        uint2 u = sp[c4];
        float2 s0 = __half22float2(*(__half2*)&u.x);
        float2 s1 = __half22float2(*(__half2*)&u.y);
        agg[4 * c4 + 0] = a.x + b.x + s0.x;
        agg[4 * c4 + 1] = a.y + b.y + s0.y;
        agg[4 * c4 + 2] = a.z + b.z + s1.x;
        agg[4 * c4 + 3] = a.w + b.w + s1.y;
    }

    // overflow fixup (nov==0 in practice)
    int nov = min(gcur[NBK * GSTR], OVFCAP);
    for (int k = 0; k < nov; ++k) {
        ull e = ovf[k];
        if ((int)(e >> 32) == i) {
            int s = (int)(e & 0xFFFFFFFFu);
            for (int c = 0; c < IC; ++c)
                agg[c] += __half2float(xph[(size_t)s * 16 + c]);
        }
    }

    float tt[IC];
#pragma unroll
    for (int c = 0; c < IC; ++c) tt[c] = dv * agg[c];

    float r[HC];
#pragma unroll
    for (int f = 0; f < HC; ++f) {
        float a = sb1[f];
#pragma unroll
        for (int c = 0; c < IC; ++c) a = fmaf(tt[c], sW1[c * HC + f], a);
        r[f] = fmaxf(a, 0.0f);
    }

    float o0 = 0.0f, o1 = 0.0f;
#pragma unroll
    for (int f = 0; f < HC; ++f) {
        o0 = fmaf(r[f], sW2[f * OC + 0], o0);
        o1 = fmaf(r[f], sW2[f * OC + 1], o1);
    }
    h2bp[i] = make_float2(o0 * dv, o1 * dv);  // dinv-prescaled for layer 2
    selfout[i] = make_float2(o0 * dv * dv + sb2[0], o1 * dv * dv + sb2[1]);
}

// layer-2: out[i] = selfout[i] + dinv[i] * (sum h2bp[src] + ovf matches).
// 2 lanes per node (split edge range), shfl_xor combine.
__global__ __launch_bounds__(256) void k_agg2(const int* __restrict__ rsg,
                                              const unsigned* __restrict__ spl,
                                              const unsigned* __restrict__ csr,
                                              const int* __restrict__ gcur,
                                              const ull* __restrict__ ovf,
                                              const float* __restrict__ dinv,
                                              const float2* __restrict__ h2bp,
                                              const float2* __restrict__ selfout,
                                              float2* __restrict__ out) {
    int tt = blockIdx.x * 256 + threadIdx.x;
    int i = tt >> 1;
    int h = tt & 1;
    if (i >= NN) return;
    unsigned sp = spl[i];
    int beg = rsg[i];
    int end = beg + (int)(sp & 0xFFFF) + (int)(sp >> 16);
    float ax = 0.0f, ay = 0.0f;
    int j = beg + h;
    for (; j + 2 < end; j += 4) {
        float2 h0 = h2bp[csr[j]];
        float2 h1 = h2bp[csr[j + 2]];
        ax += h0.x + h1.x;
        ay += h0.y + h1.y;
    }
    if (j < end) {
        float2 h0 = h2bp[csr[j]];
        ax += h0.x;
        ay += h0.y;
    }
    ax += __shfl_xor(ax, 1);
    ay += __shfl_xor(ay, 1);
    if (h == 0) {
        // overflow fixup (nov==0 in practice); h2bp already dinv[src]-prescaled
        int nov = min(gcur[NBK * GSTR], OVFCAP);
        for (int k = 0; k < nov; ++k) {
            ull e = ovf[k];
            if ((int)(e >> 32) == i) {
                float2 hh = h2bp[(int)(e & 0xFFFFFFFFu)];
                ax += hh.x;
                ay += hh.y;
            }
        }
        float dv = dinv[i];
        float2 so = selfout[i];
        out[i] = make_float2(so.x + dv * ax, so.y + dv * ay);
    }
}

extern "C" void kernel_launch(void* const* d_in, const int* in_sizes, int n_in,
                              void* d_out, int out_size, void* d_ws, size_t ws_size,
                              hipStream_t stream) {
    const float* x = (const float*)d_in[0];
    const void* ei = d_in[1];
    // d_in[2] = edge_attr (unused)
    const float* W1 = (const float*)d_in[3];
    const float* b1 = (const float*)d_in[4];
    const float* W2 = (const float*)d_in[5];
    const float* b2 = (const float*)d_in[6];
    float* out = (float*)d_out;

    ull* ovf = (ull*)d_ws;                              // OVFCAP       (0.5MB)
    int* gcur = (int*)(ovf + OVFCAP);                   // (NBK+1)*16 -> pad 6400
    int* flag = gcur + 6400;                            // 4
    int* rsg = flag + 4;                                // NN
    unsigned* spl = (unsigned*)(rsg + NN);              // NN
    float* dinv = (float*)(spl + NN);                   // NN
    __half* xph = (__half*)(dinv + NN);                 // NN*16 halves (6.4MB)
    float2* h2bp = (float2*)(xph + (size_t)NN * 16);    // NN
    float2* selfout = h2bp + NN;                        // NN
    unsigned* binned = (unsigned*)(selfout + NN);       // NBK*CAP      (28.9MB)
    float* partial = (float*)binned;                    // 2*NN*16 f32 (25.6MB), overlays
                                                        // binned (dead after k_sort)
    unsigned* csr = binned + (size_t)NBK * CAP;         // NBK*CAP      (28.9MB)

    k_init<<<2, 256, 0, stream>>>(gcur, ei, flag);
    k_binA<<<NTILE, 256, 0, stream>>>(ei, flag, gcur, binned, ovf);
    k_sort<<<NBK, 1024, 0, stream>>>(gcur, binned, ovf, csr, dinv, rsg, spl);
    k_prep<<<(NN * 16 + 255) / 256, 256, 0, stream>>>(x, dinv, xph);
    k_agg1<<<2 * NAGG, 256, 0, stream>>>(rsg, spl, csr, xph, partial);
    k_mlp<<<NB, 256, 0, stream>>>(partial, xph, gcur, ovf, dinv, W1, b1, W2, b2,
                                  h2bp, selfout);
    k_agg2<<<(NN * 2 + 255) / 256, 256, 0, stream>>>(rsg, spl, csr, gcur, ovf, dinv,
                                                     h2bp, selfout, (float2*)out);
}